// Round 16
// baseline (177.621 us; speedup 1.0000x reference)
//
#include <hip/hip_runtime.h>

// Problem constants
#define BB  16
#define JJ  32
#define HH  512
#define WW  512
#define KK  9
#define PAD 3
#define OH  510
#define OW  510

// r12 base (best: 145.4 us): full-width implicit GEMM, block = [16 j]
// [4 rows][512 px], XCD y-tile grouping swizzle, parity-split k-mapping,
// D-buffer coalesced stores, lgkm-only barriers. ONE change vs r12:
// global stores carry the non-temporal (nt) hint -- output is write-once/
// never-read, and the XCD-resident write set (~12 MB) is 3x the 4 MB L2,
// so evict-first streaming should restore write-order at DRAM and stop
// thrashing input reads (attacks residual 3.7 vs 6.6 TB/s write BW).
#define RROWS  4
#define NRAW   12
#define IN_DW  268                  // dwords per input row (264 used + pad)
#define IN_PITCH_B (IN_DW * 4)      // 1072
#define IN_BYTES (NRAW * IN_PITCH_B)   // 12864

#define D_PITCH 524                 // f32 per j-row (512 + pad)
#define DBUF_OFF IN_BYTES
#define LDS_BYTES (DBUF_OFF + 16 * D_PITCH * 4)   // 46400

// raw f32 weights [16 j][10 u][20 v'] (v' = v+1, zero-padded), union with D
#define WRAW_OFF DBUF_OFF           // 16*800 = 12800 B <= D region

typedef __bf16 bf16x8 __attribute__((ext_vector_type(8)));
typedef float  f32x4  __attribute__((ext_vector_type(4)));

__device__ __forceinline__ unsigned pack2bf(float a, float b) {
    unsigned ua = __float_as_uint(a) + 0x8000u;
    unsigned ub = __float_as_uint(b) + 0x8000u;
    return (ua >> 16) | (ub & 0xFFFF0000u);
}

// barrier waiting only on LDS ops -- global stores stay in flight (r9+)
__device__ __forceinline__ void barrier_lds_only() {
    asm volatile("s_waitcnt lgkmcnt(0)" ::: "memory");
    __builtin_amdgcn_s_barrier();
}

__global__ __launch_bounds__(256, 3)
void conv_mfma_kernel(const float* __restrict__ in,
                      const float* __restrict__ wgt,
                      float* __restrict__ out) {
    __shared__ __align__(16) char lds[LDS_BYTES];

    const int tid  = threadIdx.x;
    const int lane = tid & 63;
    const int w    = tid >> 6;     // wave 0..3
    const int c    = lane & 15;
    const int q    = lane >> 4;
    const int g    = q >> 1;
    const int h    = q & 1;
    const int par  = w >> 1;       // x parity handled by this wave

    // ---- XCD swizzle: consecutive same-XCD slots = consecutive y-tiles ----
    const int id  = blockIdx.x;            // 0..4095
    const int xcd = id & 7;
    const int wk  = xcd * 512 + (id >> 3); // bijective
    const int yt  = wk & 127;              // 0..127
    const int p   = wk >> 7;               // 0..31
    const int jg  = p & 1;
    const int bi  = p >> 1;
    const int y0  = yt * RROWS;

    // ---- zero raw-weight region ----
    {
        const uint4 z = make_uint4(0u, 0u, 0u, 0u);
        for (int idx = tid; idx < 800; idx += 256)
            *(uint4*)(lds + WRAW_OFF + idx * 16) = z;
    }
    __syncthreads();

    // ---- fill raw weights: [16 j][10 u][20 v'], v' = v+1 ----
    float* rawF = (float*)(lds + WRAW_OFF);
    const float* wB = wgt + (size_t)(bi * JJ + jg * 16) * (KK * KK);
    for (int idx = tid; idx < 16 * 81; idx += 256) {
        const int j   = idx / 81;
        const int rem = idx - j * 81;
        const int u   = rem / 9;
        const int v   = rem - u * 9;
        rawF[j * 200 + u * 20 + v + 1] = wB[idx];
    }
    __syncthreads();

    // ---- A fragments to registers: afrag[s], j = c, v = 8h + e - 1 + par ----
    bf16x8 afrag[5];
    #pragma unroll
    for (int s = 0; s < 5; ++s) {
        const int u = 2 * s + g;            // 0..9 (u=9 row stays zero)
        const int base = c * 200 + u * 20 + 8 * h + par;  // v'=v+1 folded in
        float wv[8];
        #pragma unroll
        for (int e = 0; e < 8; ++e) wv[e] = rawF[base + e];
        const uint4 pk = make_uint4(pack2bf(wv[0], wv[1]), pack2bf(wv[2], wv[3]),
                                    pack2bf(wv[4], wv[5]), pack2bf(wv[6], wv[7]));
        afrag[s] = __builtin_bit_cast(bf16x8, pk);
    }

    // ---- stage 12 full-width input rows as bf16 (elements -4..523) ----
    const float* inB = in + (size_t)bi * (HH * WW);
    #pragma unroll 1
    for (int idx = tid; idx < NRAW * 66; idx += 256) {
        const int rr = idx / 66;
        const int m  = idx - rr * 66;       // chunk: elements 8m-4 .. 8m+3
        const int gr = y0 - PAD + rr;
        float el[8];
        if ((unsigned)gr < (unsigned)HH) {
            const float* rp = inB + gr * WW + 8 * m - 4;
            if (m >= 1 && m <= 63) {        // interior: 16B-aligned float4 x2
                const float4 a = *(const float4*)rp;
                const float4 b = *(const float4*)(rp + 4);
                el[0]=a.x; el[1]=a.y; el[2]=a.z; el[3]=a.w;
                el[4]=b.x; el[5]=b.y; el[6]=b.z; el[7]=b.w;
            } else {
                #pragma unroll
                for (int t = 0; t < 8; ++t) {
                    const int gx = 8 * m - 4 + t;
                    el[t] = ((unsigned)gx < (unsigned)WW) ? rp[t] : 0.f;
                }
            }
        } else {
            #pragma unroll
            for (int t = 0; t < 8; ++t) el[t] = 0.f;
        }
        *(uint4*)(lds + rr * IN_PITCH_B + m * 16) =
            make_uint4(pack2bf(el[0], el[1]), pack2bf(el[2], el[3]),
                       pack2bf(el[4], el[5]), pack2bf(el[6], el[7]));
    }
    __syncthreads();   // weights read + input staged; D/WRAW region now free

    // ---- main loop: 4 output rows ----
    const uint* L = (const uint*)lds;
    const int dwl = c + par + 4 * h + 128 * (w & 1);
    float* D = (float*)(lds + DBUF_OFF);
    const int xb = 256 * (w & 1) + 2 * c + par;
    const size_t plane = (size_t)OH * OW;
    float* outB = out + (size_t)(bi * JJ + jg * 16) * plane;

    #pragma unroll 1
    for (int r = 0; r < RROWS; ++r) {
        f32x4 acc[8];
        #pragma unroll
        for (int i = 0; i < 8; ++i) acc[i] = (f32x4){0.f, 0.f, 0.f, 0.f};

        #pragma unroll
        for (int s = 0; s < 5; ++s) {
            int u = 2 * s + g;
            if (u > 8) u = 0;               // afrag[s]==0 there; finite B ok
            const int rowdw = (r + u) * IN_DW + dwl;
            #pragma unroll
            for (int i = 0; i < 8; ++i) {
                const int d = rowdw + 16 * i;
                const uint4 bf = make_uint4(L[d], L[d + 1], L[d + 2], L[d + 3]);
                acc[i] = __builtin_amdgcn_mfma_f32_16x16x32_bf16(
                             afrag[s], __builtin_bit_cast(bf16x8, bf), acc[i], 0, 0, 0);
            }
        }

        // D-buffer: row m = q*4+rg (j), col = pixel x
        #pragma unroll
        for (int i = 0; i < 8; ++i) {
            const int x = xb + 32 * i;
            #pragma unroll
            for (int rg = 0; rg < 4; ++rg)
                D[(q * 4 + rg) * D_PITCH + x] = acc[i][rg];
        }
        barrier_lds_only();

        // store: 4 j per wave, 4 x-segments, float2/lane, NON-TEMPORAL
        const int y = y0 + r;
        if (y < OH) {
            #pragma unroll
            for (int jj = 0; jj < 4; ++jj) {
                const int jl = w * 4 + jj;
                float* op = outB + (size_t)jl * plane + (size_t)y * OW;
                #pragma unroll
                for (int seg = 0; seg < 4; ++seg) {
                    const int px = seg * 128 + 2 * lane;
                    if (px + 1 < OW) {
                        const float2 v = *(const float2*)&D[jl * D_PITCH + px];
                        __builtin_nontemporal_store(
                            *(const unsigned long long*)&v,
                            (unsigned long long*)(op + px));
                    }
                }
            }
        }
        barrier_lds_only();
    }
}

extern "C" void kernel_launch(void* const* d_in, const int* in_sizes, int n_in,
                              void* d_out, int out_size, void* d_ws, size_t ws_size,
                              hipStream_t stream) {
    const float* inp = (const float*)d_in[0];   // [16,1,512,512] f32
    const float* wgt = (const float*)d_in[1];   // [16,32,9,9]    f32
    float* out = (float*)d_out;                 // [16,32,510,510] f32

    conv_mfma_kernel<<<dim3(4096), 256, 0, stream>>>(inp, wgt, out);
}

// Round 17
// 140.879 us; speedup vs baseline: 1.2608x; 1.2608x over previous
//
#include <hip/hip_runtime.h>

// Problem constants
#define BB  16
#define JJ  32
#define HH  512
#define WW  512
#define KK  9
#define PAD 3
#define OH  510
#define OW  510

// r12 base (best: 145.4 us) with ONE change: RROWS 4 -> 8. Halves the
// per-block prologue count (grid 4096 -> 2048) and cuts staging halo
// overhead from 12 rows/4 outputs to 16 rows/8 outputs (-33% staging
// volume device-wide). Store/compute/barrier structure per row identical.
// r16 lesson: nt-stores broke L2 write-combining (145->178) -- L2 run
// assembly is the mechanism behind r10/r12 wins; keep normal stores.
#define RROWS  8
#define NRAW   16                   // RROWS + KK - 1
#define IN_DW  268                  // dwords per input row (264 used + pad)
#define IN_PITCH_B (IN_DW * 4)      // 1072
#define IN_BYTES (NRAW * IN_PITCH_B)   // 17152

#define D_PITCH 524                 // f32 per j-row (512 + pad)
#define DBUF_OFF IN_BYTES
#define LDS_BYTES (DBUF_OFF + 16 * D_PITCH * 4)   // 17152+33536 = 50688 -> 3/CU

// raw f32 weights [16 j][10 u][20 v'] (v' = v+1, zero-padded), union with D
#define WRAW_OFF DBUF_OFF           // 16*800 = 12800 B <= D region

typedef __bf16 bf16x8 __attribute__((ext_vector_type(8)));
typedef float  f32x4  __attribute__((ext_vector_type(4)));

__device__ __forceinline__ unsigned pack2bf(float a, float b) {
    unsigned ua = __float_as_uint(a) + 0x8000u;
    unsigned ub = __float_as_uint(b) + 0x8000u;
    return (ua >> 16) | (ub & 0xFFFF0000u);
}

// barrier waiting only on LDS ops -- global stores stay in flight (r9+)
__device__ __forceinline__ void barrier_lds_only() {
    asm volatile("s_waitcnt lgkmcnt(0)" ::: "memory");
    __builtin_amdgcn_s_barrier();
}

__global__ __launch_bounds__(256, 3)
void conv_mfma_kernel(const float* __restrict__ in,
                      const float* __restrict__ wgt,
                      float* __restrict__ out) {
    __shared__ __align__(16) char lds[LDS_BYTES];

    const int tid  = threadIdx.x;
    const int lane = tid & 63;
    const int w    = tid >> 6;     // wave 0..3
    const int c    = lane & 15;
    const int q    = lane >> 4;
    const int g    = q >> 1;
    const int h    = q & 1;
    const int par  = w >> 1;       // x parity handled by this wave

    // ---- XCD swizzle: consecutive same-XCD slots = consecutive y-tiles ----
    const int id  = blockIdx.x;            // 0..2047
    const int xcd = id & 7;
    const int wk  = xcd * 256 + (id >> 3); // bijective (2048 = 8*256)
    const int yt  = wk & 63;               // 0..63
    const int p   = wk >> 6;               // 0..31
    const int jg  = p & 1;
    const int bi  = p >> 1;
    const int y0  = yt * RROWS;

    // ---- zero raw-weight region ----
    {
        const uint4 z = make_uint4(0u, 0u, 0u, 0u);
        for (int idx = tid; idx < 800; idx += 256)
            *(uint4*)(lds + WRAW_OFF + idx * 16) = z;
    }
    __syncthreads();

    // ---- fill raw weights: [16 j][10 u][20 v'], v' = v+1 ----
    float* rawF = (float*)(lds + WRAW_OFF);
    const float* wB = wgt + (size_t)(bi * JJ + jg * 16) * (KK * KK);
    for (int idx = tid; idx < 16 * 81; idx += 256) {
        const int j   = idx / 81;
        const int rem = idx - j * 81;
        const int u   = rem / 9;
        const int v   = rem - u * 9;
        rawF[j * 200 + u * 20 + v + 1] = wB[idx];
    }
    __syncthreads();

    // ---- A fragments to registers: afrag[s], j = c, v = 8h + e - 1 + par ----
    bf16x8 afrag[5];
    #pragma unroll
    for (int s = 0; s < 5; ++s) {
        const int u = 2 * s + g;            // 0..9 (u=9 row stays zero)
        const int base = c * 200 + u * 20 + 8 * h + par;  // v'=v+1 folded in
        float wv[8];
        #pragma unroll
        for (int e = 0; e < 8; ++e) wv[e] = rawF[base + e];
        const uint4 pk = make_uint4(pack2bf(wv[0], wv[1]), pack2bf(wv[2], wv[3]),
                                    pack2bf(wv[4], wv[5]), pack2bf(wv[6], wv[7]));
        afrag[s] = __builtin_bit_cast(bf16x8, pk);
    }

    // ---- stage 16 full-width input rows as bf16 (elements -4..523) ----
    const float* inB = in + (size_t)bi * (HH * WW);
    #pragma unroll 1
    for (int idx = tid; idx < NRAW * 66; idx += 256) {
        const int rr = idx / 66;
        const int m  = idx - rr * 66;       // chunk: elements 8m-4 .. 8m+3
        const int gr = y0 - PAD + rr;
        float el[8];
        if ((unsigned)gr < (unsigned)HH) {
            const float* rp = inB + gr * WW + 8 * m - 4;
            if (m >= 1 && m <= 63) {        // interior: 16B-aligned float4 x2
                const float4 a = *(const float4*)rp;
                const float4 b = *(const float4*)(rp + 4);
                el[0]=a.x; el[1]=a.y; el[2]=a.z; el[3]=a.w;
                el[4]=b.x; el[5]=b.y; el[6]=b.z; el[7]=b.w;
            } else {
                #pragma unroll
                for (int t = 0; t < 8; ++t) {
                    const int gx = 8 * m - 4 + t;
                    el[t] = ((unsigned)gx < (unsigned)WW) ? rp[t] : 0.f;
                }
            }
        } else {
            #pragma unroll
            for (int t = 0; t < 8; ++t) el[t] = 0.f;
        }
        *(uint4*)(lds + rr * IN_PITCH_B + m * 16) =
            make_uint4(pack2bf(el[0], el[1]), pack2bf(el[2], el[3]),
                       pack2bf(el[4], el[5]), pack2bf(el[6], el[7]));
    }
    __syncthreads();   // weights read + input staged; D/WRAW region now free

    // ---- main loop: 8 output rows ----
    const uint* L = (const uint*)lds;
    const int dwl = c + par + 4 * h + 128 * (w & 1);
    float* D = (float*)(lds + DBUF_OFF);
    const int xb = 256 * (w & 1) + 2 * c + par;
    const size_t plane = (size_t)OH * OW;
    float* outB = out + (size_t)(bi * JJ + jg * 16) * plane;

    #pragma unroll 1
    for (int r = 0; r < RROWS; ++r) {
        f32x4 acc[8];
        #pragma unroll
        for (int i = 0; i < 8; ++i) acc[i] = (f32x4){0.f, 0.f, 0.f, 0.f};

        #pragma unroll
        for (int s = 0; s < 5; ++s) {
            int u = 2 * s + g;
            if (u > 8) u = 0;               // afrag[s]==0 there; finite B ok
            const int rowdw = (r + u) * IN_DW + dwl;
            #pragma unroll
            for (int i = 0; i < 8; ++i) {
                const int d = rowdw + 16 * i;
                const uint4 bf = make_uint4(L[d], L[d + 1], L[d + 2], L[d + 3]);
                acc[i] = __builtin_amdgcn_mfma_f32_16x16x32_bf16(
                             afrag[s], __builtin_bit_cast(bf16x8, bf), acc[i], 0, 0, 0);
            }
        }

        // D-buffer: row m = q*4+rg (j), col = pixel x
        #pragma unroll
        for (int i = 0; i < 8; ++i) {
            const int x = xb + 32 * i;
            #pragma unroll
            for (int rg = 0; rg < 4; ++rg)
                D[(q * 4 + rg) * D_PITCH + x] = acc[i][rg];
        }
        barrier_lds_only();

        // store: 4 j per wave, 4 x-segments, float2/lane (512B/inst)
        const int y = y0 + r;
        if (y < OH) {
            #pragma unroll
            for (int jj = 0; jj < 4; ++jj) {
                const int jl = w * 4 + jj;
                float* op = outB + (size_t)jl * plane + (size_t)y * OW;
                #pragma unroll
                for (int seg = 0; seg < 4; ++seg) {
                    const int px = seg * 128 + 2 * lane;
                    if (px + 1 < OW)
                        *(float2*)(op + px) = *(const float2*)&D[jl * D_PITCH + px];
                }
            }
        }
        barrier_lds_only();
    }
}

extern "C" void kernel_launch(void* const* d_in, const int* in_sizes, int n_in,
                              void* d_out, int out_size, void* d_ws, size_t ws_size,
                              hipStream_t stream) {
    const float* inp = (const float*)d_in[0];   // [16,1,512,512] f32
    const float* wgt = (const float*)d_in[1];   // [16,32,9,9]    f32
    float* out = (float*)d_out;                 // [16,32,510,510] f32

    conv_mfma_kernel<<<dim3(2048), 256, 0, stream>>>(inp, wgt, out);
}